// Round 2
// baseline (1878.884 us; speedup 1.0000x reference)
//
#include <hip/hip_runtime.h>
#include <math.h>

#define BB 2048
#define SS 96
#define DD 7
#define HH 64
#define H2 16
#define G1 256   // 4*HH
#define G2 64    // 4*H2
#define LOST 65  // padded stride for [96][64] LDS tiles

__device__ __forceinline__ float sigm(float x) { return 1.0f / (1.0f + __expf(-x)); }
__device__ __forceinline__ float tanh_f(float x) { return 1.0f - 2.0f / (__expf(2.0f * x) + 1.0f); }

// ---------------- Kernel 1: feature attention ----------------
// fa[b,s,j] = tanh( sum_i v[s,i]*att[i,j] + x[s,j] )
__global__ __launch_bounds__(256) void k_feat(
    const float* __restrict__ x,
    const float* __restrict__ fv_w, const float* __restrict__ fv_b,
    const float* __restrict__ fk_w, const float* __restrict__ fk_b,
    const float* __restrict__ fq_w, const float* __restrict__ fq_b,
    float* __restrict__ fa_out)
{
    __shared__ float xs[SS * DD], vs[SS * DD], ks[SS * DD], qs[SS * DD];
    __shared__ float att[DD * DD];
    __shared__ float wv[DD * DD], wk[DD * DD], wq[DD * DD];
    __shared__ float bv[DD], bk[DD], bq[DD];
    const int b = blockIdx.x, t = threadIdx.x;
    const float* xb = x + (size_t)b * SS * DD;

    for (int idx = t; idx < SS * DD; idx += 256) xs[idx] = xb[idx];
    if (t < DD * DD) { wv[t] = fv_w[t]; wk[t] = fk_w[t]; wq[t] = fq_w[t]; }
    if (t < DD)      { bv[t] = fv_b[t]; bk[t] = fk_b[t]; bq[t] = fq_b[t]; }
    __syncthreads();

    // v = x @ fv_w^T + fv_b
    for (int idx = t; idx < SS * DD; idx += 256) {
        int s = idx / DD, j = idx % DD;
        float a = bv[j];
        #pragma unroll
        for (int i = 0; i < DD; i++) a += xs[s * DD + i] * wv[j * DD + i];
        vs[idx] = a;
    }
    __syncthreads();
    // k = (x+v) @ fk_w^T + fk_b
    for (int idx = t; idx < SS * DD; idx += 256) {
        int s = idx / DD, j = idx % DD;
        float a = bk[j];
        #pragma unroll
        for (int i = 0; i < DD; i++) a += (xs[s * DD + i] + vs[s * DD + i]) * wk[j * DD + i];
        ks[idx] = a;
    }
    __syncthreads();
    // q = (x+k) @ fq_w^T + fq_b
    for (int idx = t; idx < SS * DD; idx += 256) {
        int s = idx / DD, j = idx % DD;
        float a = bq[j];
        #pragma unroll
        for (int i = 0; i < DD; i++) a += (xs[s * DD + i] + ks[s * DD + i]) * wq[j * DD + i];
        qs[idx] = a;
    }
    __syncthreads();
    // scores[i,j] = sum_s q[s,i]*k[s,j]
    if (t < DD * DD) {
        int i = t / DD, j = t % DD;
        float a = 0.0f;
        for (int s = 0; s < SS; s++) a += qs[s * DD + i] * ks[s * DD + j];
        att[t] = a;
    }
    __syncthreads();
    // softmax over j per row i
    if (t < DD) {
        float m = -1e30f;
        #pragma unroll
        for (int j = 0; j < DD; j++) m = fmaxf(m, att[t * DD + j]);
        float e[DD]; float sum = 0.0f;
        #pragma unroll
        for (int j = 0; j < DD; j++) { e[j] = __expf(att[t * DD + j] - m); sum += e[j]; }
        float inv = 1.0f / sum;
        #pragma unroll
        for (int j = 0; j < DD; j++) att[t * DD + j] = e[j] * inv;
    }
    __syncthreads();
    // fa = tanh(v @ att + x)
    for (int idx = t; idx < SS * DD; idx += 256) {
        int s = idx / DD, j = idx % DD;
        float a = xs[idx];
        #pragma unroll
        for (int i = 0; i < DD; i++) a += vs[s * DD + i] * att[i * DD + j];
        fa_out[(size_t)b * SS * DD + idx] = tanh_f(a);
    }
}

// ---------------- Kernel 2: bidirectional LSTM (H=64) ----------------
// 512 threads: t<256 forward dir, t>=256 backward dir. Thread g owns gate row g.
__global__ __launch_bounds__(512) void k_bilstm(
    const float* __restrict__ fa,
    const float* __restrict__ wih_f, const float* __restrict__ whh_f,
    const float* __restrict__ bih_f, const float* __restrict__ bhh_f,
    const float* __restrict__ wih_b, const float* __restrict__ whh_b,
    const float* __restrict__ bih_b, const float* __restrict__ bhh_b,
    float* __restrict__ lo_out)
{
    __shared__ float fas[SS * DD];        // 672
    __shared__ float hbuf[2][HH];
    __shared__ float cbuf[2][HH];
    __shared__ float gates[2][G1];
    __shared__ float hs[2][SS][HH];       // 49 KB

    const int b = blockIdx.x, t = threadIdx.x;
    const int dir = t >> 8;               // 0 fwd, 1 bwd
    const int g = t & 255;

    for (int idx = t; idx < SS * DD; idx += 512) fas[idx] = fa[(size_t)b * SS * DD + idx];

    const float* wih = dir ? wih_b : wih_f;
    const float* whh = dir ? whh_b : whh_f;
    float wr[HH];
    #pragma unroll
    for (int j = 0; j < HH; j++) wr[j] = whh[g * HH + j];
    float wx[DD];
    #pragma unroll
    for (int i = 0; i < DD; i++) wx[i] = wih[g * DD + i];
    const float bias = dir ? (bih_b[g] + bhh_b[g]) : (bih_f[g] + bhh_f[g]);

    if (g < HH) { hbuf[dir][g] = 0.0f; cbuf[dir][g] = 0.0f; }
    __syncthreads();

    for (int step = 0; step < SS; step++) {
        const int s = dir ? (SS - 1 - step) : step;
        float a = bias;
        #pragma unroll
        for (int i = 0; i < DD; i++) a += fas[s * DD + i] * wx[i];
        float a0 = 0.f, a1 = 0.f, a2 = 0.f, a3 = 0.f;
        #pragma unroll
        for (int j = 0; j < HH; j += 4) {
            a0 += hbuf[dir][j]     * wr[j];
            a1 += hbuf[dir][j + 1] * wr[j + 1];
            a2 += hbuf[dir][j + 2] * wr[j + 2];
            a3 += hbuf[dir][j + 3] * wr[j + 3];
        }
        a += (a0 + a1) + (a2 + a3);
        gates[dir][g] = a;
        __syncthreads();
        if (g < HH) {
            const int j = g;
            float iv = sigm(gates[dir][j]);
            float fv = sigm(gates[dir][HH + j]);
            float gv = tanh_f(gates[dir][2 * HH + j]);
            float ov = sigm(gates[dir][3 * HH + j]);
            float c = fv * cbuf[dir][j] + iv * gv;
            float h = ov * tanh_f(c);
            cbuf[dir][j] = c;
            hbuf[dir][j] = h;
            hs[dir][s][j] = h;
        }
        __syncthreads();
    }

    for (int idx = t; idx < SS * HH; idx += 512) {
        int s = idx / HH, j = idx % HH;
        lo_out[(size_t)b * SS * HH + idx] = 0.5f * (hs[0][s][j] + hs[1][s][j]);
    }
}

// ---------------- Kernel 3: temporal attention + LSTM2 + fc ----------------
__global__ __launch_bounds__(256) void k_temporal(
    const float* __restrict__ lo_g,
    const float* __restrict__ tv_w, const float* __restrict__ tv_b,
    const float* __restrict__ tk_w, const float* __restrict__ tk_b,
    const float* __restrict__ tq_w, const float* __restrict__ tq_b,
    const float* __restrict__ l2_wih, const float* __restrict__ l2_whh,
    const float* __restrict__ l2_bih, const float* __restrict__ l2_bhh,
    const float* __restrict__ fc_w, const float* __restrict__ fc_b,
    float* __restrict__ out)
{
    __shared__ float lo[SS * LOST];   // later reused as xg2[s][g]
    __shared__ float tvb[SS * LOST];
    __shared__ float tkb[SS * LOST];
    __shared__ float tqb[SS * LOST];  // later reused as 'to'
    __shared__ float prow[4][SS];
    __shared__ float hsb[SS * H2];

    const int b = blockIdx.x, t = threadIdx.x;
    const int lane = t & 63, w = t >> 6;

    for (int idx = t; idx < SS * HH; idx += 256) {
        int s = idx >> 6, d = idx & 63;
        lo[s * LOST + d] = lo_g[(size_t)b * SS * HH + idx];
    }
    __syncthreads();

    // Phase A: tv, tk, tq  (lane j holds weight column w[j][:] in regs)
    for (int m = 0; m < 3; m++) {
        const float* wm = (m == 0) ? tv_w : (m == 1) ? tk_w : tq_w;
        const float* bm = (m == 0) ? tv_b : (m == 1) ? tk_b : tq_b;
        float* ob = (m == 0) ? tvb : (m == 1) ? tkb : tqb;
        float wreg[HH];
        #pragma unroll
        for (int d = 0; d < HH; d++) wreg[d] = wm[lane * HH + d];
        float bb = bm[lane];
        for (int s = w; s < SS; s += 4) {
            float a0 = 0.f, a1 = 0.f, a2 = 0.f, a3 = 0.f;
            #pragma unroll
            for (int d = 0; d < HH; d += 4) {
                a0 += lo[s * LOST + d]     * wreg[d];
                a1 += lo[s * LOST + d + 1] * wreg[d + 1];
                a2 += lo[s * LOST + d + 2] * wreg[d + 2];
                a3 += lo[s * LOST + d + 3] * wreg[d + 3];
            }
            ob[s * LOST + lane] = bb + ((a0 + a1) + (a2 + a3));
        }
        __syncthreads();
    }

    // Phase B: per row i (wave-parallel): scores -> softmax -> PV; write 'to' into tqb
    for (int i = w; i < SS; i += 4) {
        const int j1 = lane;
        const int j2 = HH + (lane & 31);   // rows 64..95 (lanes<32)
        float s1a = 0.f, s1b = 0.f, s2a = 0.f, s2b = 0.f;
        #pragma unroll
        for (int d = 0; d < HH; d += 2) {
            float qa = tqb[i * LOST + d], qb2 = tqb[i * LOST + d + 1];
            s1a += qa  * tkb[j1 * LOST + d];
            s1b += qb2 * tkb[j1 * LOST + d + 1];
            s2a += qa  * tkb[j2 * LOST + d];
            s2b += qb2 * tkb[j2 * LOST + d + 1];
        }
        float s1 = s1a + s1b;
        float s2 = (lane < 32) ? (s2a + s2b) : -1e30f;
        float m = fmaxf(s1, s2);
        #pragma unroll
        for (int off = 32; off > 0; off >>= 1) m = fmaxf(m, __shfl_xor(m, off));
        float e1 = __expf(s1 - m);
        float e2 = (lane < 32) ? __expf(s2 - m) : 0.0f;
        float sum = e1 + e2;
        #pragma unroll
        for (int off = 32; off > 0; off >>= 1) sum += __shfl_xor(sum, off);
        float inv = 1.0f / sum;
        prow[w][lane] = e1 * inv;
        if (lane < 32) prow[w][HH + lane] = e2 * inv;
        __syncthreads();
        // PV: lane = output dim d
        float a0 = 0.f, a1 = 0.f;
        #pragma unroll
        for (int j = 0; j < SS; j += 2) {
            a0 += prow[w][j]     * tvb[j * LOST + lane];
            a1 += prow[w][j + 1] * tvb[(j + 1) * LOST + lane];
        }
        float tov = tanh_f(a0 + a1);
        __syncthreads();
        tqb[i * LOST + lane] = tov;    // overwrite tq row i (only this wave reads it)
        __syncthreads();
    }
    __syncthreads();

    // Phase C: xg2[s][g] = bias_g + sum_d to[s][d]*l2_wih[g][d]  -> into lo buffer
    {
        float wreg[HH];
        #pragma unroll
        for (int d = 0; d < HH; d++) wreg[d] = l2_wih[lane * HH + d];
        float bb = l2_bih[lane] + l2_bhh[lane];
        for (int s = w; s < SS; s += 4) {
            float a0 = 0.f, a1 = 0.f, a2 = 0.f, a3 = 0.f;
            #pragma unroll
            for (int d = 0; d < HH; d += 4) {
                a0 += tqb[s * LOST + d]     * wreg[d];
                a1 += tqb[s * LOST + d + 1] * wreg[d + 1];
                a2 += tqb[s * LOST + d + 2] * wreg[d + 2];
                a3 += tqb[s * LOST + d + 3] * wreg[d + 3];
            }
            lo[s * LOST + lane] = bb + ((a0 + a1) + (a2 + a3));
        }
    }
    __syncthreads();

    // Phase D: LSTM2 scan, single wave, shuffles only (h,c replicated: lane L holds unit L&15)
    if (t < 64) {
        float whr[H2];
        #pragma unroll
        for (int j = 0; j < H2; j++) whr[j] = l2_whh[lane * H2 + j];
        const int myi = lane & 15;
        float h = 0.0f, c = 0.0f;
        for (int s = 0; s < SS; s++) {
            float a = lo[s * LOST + lane];
            #pragma unroll
            for (int j = 0; j < H2; j++) a += __shfl(h, j) * whr[j];
            float iv = __shfl(a, myi);
            float fv = __shfl(a, H2 + myi);
            float gv = __shfl(a, 2 * H2 + myi);
            float ov = __shfl(a, 3 * H2 + myi);
            c = sigm(fv) * c + sigm(iv) * tanh_f(gv);
            h = sigm(ov) * tanh_f(c);
            if (lane < H2) hsb[s * H2 + lane] = h;
        }
    }
    __syncthreads();

    // Phase E: fc  out[b,s,d] = sum_j hsb[s,j]*fc_w[d,j] + fc_b[d]
    for (int idx = t; idx < SS * DD; idx += 256) {
        int s = idx / DD, d = idx % DD;
        float a = fc_b[d];
        #pragma unroll
        for (int j = 0; j < H2; j++) a += hsb[s * H2 + j] * fc_w[d * H2 + j];
        out[(size_t)b * SS * DD + idx] = a;
    }
}

extern "C" void kernel_launch(void* const* d_in, const int* in_sizes, int n_in,
                              void* d_out, int out_size, void* d_ws, size_t ws_size,
                              hipStream_t stream) {
    const float* x     = (const float*)d_in[0];
    const float* fv_w  = (const float*)d_in[1];
    const float* fv_b  = (const float*)d_in[2];
    const float* fk_w  = (const float*)d_in[3];
    const float* fk_b  = (const float*)d_in[4];
    const float* fq_w  = (const float*)d_in[5];
    const float* fq_b  = (const float*)d_in[6];
    const float* l1f_wih = (const float*)d_in[7];
    const float* l1f_whh = (const float*)d_in[8];
    const float* l1f_bih = (const float*)d_in[9];
    const float* l1f_bhh = (const float*)d_in[10];
    const float* l1b_wih = (const float*)d_in[11];
    const float* l1b_whh = (const float*)d_in[12];
    const float* l1b_bih = (const float*)d_in[13];
    const float* l1b_bhh = (const float*)d_in[14];
    const float* tv_w  = (const float*)d_in[15];
    const float* tv_b  = (const float*)d_in[16];
    const float* tk_w  = (const float*)d_in[17];
    const float* tk_b  = (const float*)d_in[18];
    const float* tq_w  = (const float*)d_in[19];
    const float* tq_b  = (const float*)d_in[20];
    const float* l2_wih = (const float*)d_in[21];
    const float* l2_whh = (const float*)d_in[22];
    const float* l2_bih = (const float*)d_in[23];
    const float* l2_bhh = (const float*)d_in[24];
    const float* fc_w  = (const float*)d_in[25];
    const float* fc_b  = (const float*)d_in[26];

    float* fa = (float*)d_ws;                       // B*S*D floats
    float* lo = fa + (size_t)BB * SS * DD;          // B*S*H floats

    k_feat<<<BB, 256, 0, stream>>>(x, fv_w, fv_b, fk_w, fk_b, fq_w, fq_b, fa);
    k_bilstm<<<BB, 512, 0, stream>>>(fa,
        l1f_wih, l1f_whh, l1f_bih, l1f_bhh,
        l1b_wih, l1b_whh, l1b_bih, l1b_bhh, lo);
    k_temporal<<<BB, 256, 0, stream>>>(lo,
        tv_w, tv_b, tk_w, tk_b, tq_w, tq_b,
        l2_wih, l2_whh, l2_bih, l2_bhh, fc_w, fc_b,
        (float*)d_out);
}

// Round 3
// 1722.706 us; speedup vs baseline: 1.0907x; 1.0907x over previous
//
#include <hip/hip_runtime.h>
#include <math.h>

#define BB 2048
#define SS 96
#define DD 7
#define HH 64
#define H2 16
#define G1 256   // 4*HH
#define PAD 65   // [96][65] padded tiles (stride 65 -> 2-way bank alias = free)
#define TPAD 97  // tkT [64][97]

__device__ __forceinline__ float sigm(float x) { return 1.0f / (1.0f + __expf(-x)); }
__device__ __forceinline__ float tanh_f(float x) { return 1.0f - 2.0f / (__expf(2.0f * x) + 1.0f); }
// broadcast lane l of v to all lanes via SGPR (VALU, not LDS pipe)
__device__ __forceinline__ float rl(float v, int l) {
    return __int_as_float(__builtin_amdgcn_readlane(__float_as_int(v), l));
}

// ---------------- Kernel 1: feature attention ----------------
__global__ __launch_bounds__(256) void k_feat(
    const float* __restrict__ x,
    const float* __restrict__ fv_w, const float* __restrict__ fv_b,
    const float* __restrict__ fk_w, const float* __restrict__ fk_b,
    const float* __restrict__ fq_w, const float* __restrict__ fq_b,
    float* __restrict__ fa_out)
{
    __shared__ float xs[SS * DD], vs[SS * DD], ks[SS * DD], qs[SS * DD];
    __shared__ float att[DD * DD];
    __shared__ float wv[DD * DD], wk[DD * DD], wq[DD * DD];
    __shared__ float bv[DD], bk[DD], bq[DD];
    const int b = blockIdx.x, t = threadIdx.x;
    const float* xb = x + (size_t)b * SS * DD;

    for (int idx = t; idx < SS * DD; idx += 256) xs[idx] = xb[idx];
    if (t < DD * DD) { wv[t] = fv_w[t]; wk[t] = fk_w[t]; wq[t] = fq_w[t]; }
    if (t < DD)      { bv[t] = fv_b[t]; bk[t] = fk_b[t]; bq[t] = fq_b[t]; }
    __syncthreads();

    for (int idx = t; idx < SS * DD; idx += 256) {
        int s = idx / DD, j = idx % DD;
        float a = bv[j];
        #pragma unroll
        for (int i = 0; i < DD; i++) a += xs[s * DD + i] * wv[j * DD + i];
        vs[idx] = a;
    }
    __syncthreads();
    for (int idx = t; idx < SS * DD; idx += 256) {
        int s = idx / DD, j = idx % DD;
        float a = bk[j];
        #pragma unroll
        for (int i = 0; i < DD; i++) a += (xs[s * DD + i] + vs[s * DD + i]) * wk[j * DD + i];
        ks[idx] = a;
    }
    __syncthreads();
    for (int idx = t; idx < SS * DD; idx += 256) {
        int s = idx / DD, j = idx % DD;
        float a = bq[j];
        #pragma unroll
        for (int i = 0; i < DD; i++) a += (xs[s * DD + i] + ks[s * DD + i]) * wq[j * DD + i];
        qs[idx] = a;
    }
    __syncthreads();
    if (t < DD * DD) {
        int i = t / DD, j = t % DD;
        float a = 0.0f;
        for (int s = 0; s < SS; s++) a += qs[s * DD + i] * ks[s * DD + j];
        att[t] = a;
    }
    __syncthreads();
    if (t < DD) {
        float m = -1e30f;
        #pragma unroll
        for (int j = 0; j < DD; j++) m = fmaxf(m, att[t * DD + j]);
        float e[DD]; float sum = 0.0f;
        #pragma unroll
        for (int j = 0; j < DD; j++) { e[j] = __expf(att[t * DD + j] - m); sum += e[j]; }
        float inv = 1.0f / sum;
        #pragma unroll
        for (int j = 0; j < DD; j++) att[t * DD + j] = e[j] * inv;
    }
    __syncthreads();
    for (int idx = t; idx < SS * DD; idx += 256) {
        int s = idx / DD, j = idx % DD;
        float a = xs[idx];
        #pragma unroll
        for (int i = 0; i < DD; i++) a += vs[s * DD + i] * att[i * DD + j];
        fa_out[(size_t)b * SS * DD + idx] = tanh_f(a);
    }
}

// ---------------- Kernel 2: bidirectional LSTM (H=64) ----------------
// h broadcast via 1 lane-distributed ds_read + 64 v_readlane (not 64 LDS broadcasts)
__global__ __launch_bounds__(512) void k_bilstm(
    const float* __restrict__ fa,
    const float* __restrict__ wih_f, const float* __restrict__ whh_f,
    const float* __restrict__ bih_f, const float* __restrict__ bhh_f,
    const float* __restrict__ wih_b, const float* __restrict__ whh_b,
    const float* __restrict__ bih_b, const float* __restrict__ bhh_b,
    float* __restrict__ lo_out)
{
    __shared__ float fas[SS * DD];
    __shared__ float hbuf[2][HH];
    __shared__ float cbuf[2][HH];
    __shared__ float gates[2][G1];
    __shared__ float hs[2][SS][HH];

    const int b = blockIdx.x, t = threadIdx.x;
    const int dir = t >> 8;
    const int g = t & 255;
    const int lane = t & 63;

    for (int idx = t; idx < SS * DD; idx += 512) fas[idx] = fa[(size_t)b * SS * DD + idx];

    const float* wih = dir ? wih_b : wih_f;
    const float* whh = dir ? whh_b : whh_f;
    float wr[HH];
    #pragma unroll
    for (int j = 0; j < HH; j++) wr[j] = whh[g * HH + j];
    float wx[DD];
    #pragma unroll
    for (int i = 0; i < DD; i++) wx[i] = wih[g * DD + i];
    const float bias = dir ? (bih_b[g] + bhh_b[g]) : (bih_f[g] + bhh_f[g]);

    if (g < HH) { hbuf[dir][g] = 0.0f; cbuf[dir][g] = 0.0f; }
    __syncthreads();

    for (int step = 0; step < SS; step++) {
        const int s = dir ? (SS - 1 - step) : step;
        // fa row: one lane-distributed read, broadcast by readlane
        float freg = fas[s * DD + (lane < DD ? lane : DD - 1)];
        float a = bias;
        #pragma unroll
        for (int i = 0; i < DD; i++) a += rl(freg, i) * wx[i];
        // h row: one lane-distributed read, broadcast by readlane
        float hreg = hbuf[dir][lane];
        float b0 = 0.f, b1 = 0.f, b2 = 0.f, b3 = 0.f;
        #pragma unroll
        for (int j = 0; j < HH; j += 4) {
            b0 += rl(hreg, j)     * wr[j];
            b1 += rl(hreg, j + 1) * wr[j + 1];
            b2 += rl(hreg, j + 2) * wr[j + 2];
            b3 += rl(hreg, j + 3) * wr[j + 3];
        }
        a += (b0 + b1) + (b2 + b3);
        gates[dir][g] = a;
        __syncthreads();
        if (g < HH) {
            const int j = g;
            float iv = sigm(gates[dir][j]);
            float fv = sigm(gates[dir][HH + j]);
            float gv = tanh_f(gates[dir][2 * HH + j]);
            float ov = sigm(gates[dir][3 * HH + j]);
            float c = fv * cbuf[dir][j] + iv * gv;
            float h = ov * tanh_f(c);
            cbuf[dir][j] = c;
            hbuf[dir][j] = h;
            hs[dir][s][j] = h;
        }
        __syncthreads();
    }

    for (int idx = t; idx < SS * HH; idx += 512) {
        int s = idx / HH, j = idx % HH;
        lo_out[(size_t)b * SS * HH + idx] = 0.5f * (hs[0][s][j] + hs[1][s][j]);
    }
}

// ---------------- Kernel 3: temporal attention + LSTM2 + fc ----------------
// 8 waves. SGPR weights for weight-matmuls (lane = seq row), readlane for data dots.
// LDS: loB(lo->to) + tkT(tk transposed) + tvB(tv->xg2) + hsb = 81,280 B -> 2 blocks/CU.
__global__ __launch_bounds__(512, 4) void k_temporal(
    const float* __restrict__ lo_g,
    const float* __restrict__ tv_w, const float* __restrict__ tv_b,
    const float* __restrict__ tk_w, const float* __restrict__ tk_b,
    const float* __restrict__ tq_w, const float* __restrict__ tq_b,
    const float* __restrict__ l2_wih, const float* __restrict__ l2_whh,
    const float* __restrict__ l2_bih, const float* __restrict__ l2_bhh,
    const float* __restrict__ fc_w, const float* __restrict__ fc_b,
    float* __restrict__ out)
{
    __shared__ float loB[SS * PAD];    // lo, then 'to' (row-wise overwrite)
    __shared__ float tkT[HH * TPAD];   // tk transposed: tkT[f][P]
    __shared__ float tvB[SS * PAD];    // tv, then xg2
    __shared__ float hsb[SS * 17];

    const int b = blockIdx.x, t = threadIdx.x;
    const int lane = t & 63, w = t >> 6;

    // ---- fill loB (padded) from global, float4 ----
    const float4* lo_src = (const float4*)(lo_g + (size_t)b * SS * HH);
    #pragma unroll
    for (int k = 0; k < 3; k++) {
        int idx4 = t + 512 * k;               // [0,1536)
        float4 v = lo_src[idx4];
        int s = idx4 >> 4, d = (idx4 & 15) * 4;
        loB[s * PAD + d]     = v.x;
        loB[s * PAD + d + 1] = v.y;
        loB[s * PAD + d + 2] = v.z;
        loB[s * PAD + d + 3] = v.w;
    }
    __syncthreads();

    // ---- Phase A: tv (waves 0-1) and tk (waves 2-3), SGPR weights ----
    if (w < 4) {
        const float* wmat = (w < 2) ? tv_w : tk_w;
        const float* bvec = (w < 2) ? tv_b : tk_b;
        const int srow = (w & 1) * 64 + lane;
        if (srow < SS) {
            float lorow[HH];
            #pragma unroll
            for (int d = 0; d < HH; d++) lorow[d] = loB[srow * PAD + d];
            for (int j = 0; j < HH; j++) {
                float a0 = 0.f, a1 = 0.f, a2 = 0.f, a3 = 0.f;
                #pragma unroll
                for (int d = 0; d < HH; d += 4) {
                    a0 += lorow[d]     * wmat[j * HH + d];
                    a1 += lorow[d + 1] * wmat[j * HH + d + 1];
                    a2 += lorow[d + 2] * wmat[j * HH + d + 2];
                    a3 += lorow[d + 3] * wmat[j * HH + d + 3];
                }
                float a = bvec[j] + (a0 + a1) + (a2 + a3);
                if (w < 2) tvB[srow * PAD + j] = a;
                else       tkT[j * TPAD + srow] = a;
            }
        }
    }
    // ---- all waves: wq -> regs (lane f holds tq_w[f][0..63]); L2-hot gather ----
    float wq[HH];
    #pragma unroll
    for (int e = 0; e < HH; e++) wq[e] = tq_w[lane * HH + e];
    const float qbias = tq_b[lane];
    __syncthreads();

    // ---- Phase B: per 4-row group: q -> scores -> softmax -> PV -> 'to' ----
    for (int gi = 0; gi < 3; gi++) {
        const int i0 = 4 * (w + 8 * gi);
        // q for 4 rows: lane f accumulates q_i[f]
        float lr0 = loB[(i0 + 0) * PAD + lane];
        float lr1 = loB[(i0 + 1) * PAD + lane];
        float lr2 = loB[(i0 + 2) * PAD + lane];
        float lr3 = loB[(i0 + 3) * PAD + lane];
        float q0 = qbias, q1 = qbias, q2 = qbias, q3 = qbias;
        #pragma unroll
        for (int e = 0; e < HH; e++) {
            float we = wq[e];
            q0 += rl(lr0, e) * we;
            q1 += rl(lr1, e) * we;
            q2 += rl(lr2, e) * we;
            q3 += rl(lr3, e) * we;
        }
        // scores: lane = key pos P (and P2 = 64+(lane&31) on second acc)
        const int p2i = 64 + (lane & 31);
        float a10 = 0.f, a11 = 0.f, a12 = 0.f, a13 = 0.f;
        float a20 = 0.f, a21 = 0.f, a22 = 0.f, a23 = 0.f;
        for (int f = 0; f < HH; f++) {
            float t1 = tkT[f * TPAD + lane];
            float t2 = tkT[f * TPAD + p2i];
            float s0 = rl(q0, f), s1 = rl(q1, f), s2 = rl(q2, f), s3 = rl(q3, f);
            a10 += s0 * t1; a20 += s0 * t2;
            a11 += s1 * t1; a21 += s1 * t2;
            a12 += s2 * t1; a22 += s2 * t2;
            a13 += s3 * t1; a23 += s3 * t2;
        }
        // softmax over 96 per row (in-wave, no barriers)
        float p10, p11, p12, p13, p20, p21, p22, p23;
        {
            float m, s, e1, e2, iv;
            m = fmaxf(a10, a20);
            #pragma unroll
            for (int o = 32; o; o >>= 1) m = fmaxf(m, __shfl_xor(m, o));
            e1 = __expf(a10 - m); e2 = __expf(a20 - m);
            s = e1 + ((lane < 32) ? e2 : 0.0f);
            #pragma unroll
            for (int o = 32; o; o >>= 1) s += __shfl_xor(s, o);
            iv = 1.0f / s; p10 = e1 * iv; p20 = e2 * iv;

            m = fmaxf(a11, a21);
            #pragma unroll
            for (int o = 32; o; o >>= 1) m = fmaxf(m, __shfl_xor(m, o));
            e1 = __expf(a11 - m); e2 = __expf(a21 - m);
            s = e1 + ((lane < 32) ? e2 : 0.0f);
            #pragma unroll
            for (int o = 32; o; o >>= 1) s += __shfl_xor(s, o);
            iv = 1.0f / s; p11 = e1 * iv; p21 = e2 * iv;

            m = fmaxf(a12, a22);
            #pragma unroll
            for (int o = 32; o; o >>= 1) m = fmaxf(m, __shfl_xor(m, o));
            e1 = __expf(a12 - m); e2 = __expf(a22 - m);
            s = e1 + ((lane < 32) ? e2 : 0.0f);
            #pragma unroll
            for (int o = 32; o; o >>= 1) s += __shfl_xor(s, o);
            iv = 1.0f / s; p12 = e1 * iv; p22 = e2 * iv;

            m = fmaxf(a13, a23);
            #pragma unroll
            for (int o = 32; o; o >>= 1) m = fmaxf(m, __shfl_xor(m, o));
            e1 = __expf(a13 - m); e2 = __expf(a23 - m);
            s = e1 + ((lane < 32) ? e2 : 0.0f);
            #pragma unroll
            for (int o = 32; o; o >>= 1) s += __shfl_xor(s, o);
            iv = 1.0f / s; p13 = e1 * iv; p23 = e2 * iv;
        }
        // PV: lane = feature f; p broadcast via readlane
        float o0 = 0.f, o1 = 0.f, o2 = 0.f, o3 = 0.f;
        for (int P = 0; P < 64; P++) {
            float tvv = tvB[P * PAD + lane];
            o0 += rl(p10, P) * tvv;
            o1 += rl(p11, P) * tvv;
            o2 += rl(p12, P) * tvv;
            o3 += rl(p13, P) * tvv;
        }
        for (int P = 0; P < 32; P++) {
            float tvv = tvB[(64 + P) * PAD + lane];
            o0 += rl(p20, P) * tvv;
            o1 += rl(p21, P) * tvv;
            o2 += rl(p22, P) * tvv;
            o3 += rl(p23, P) * tvv;
        }
        loB[(i0 + 0) * PAD + lane] = tanh_f(o0);
        loB[(i0 + 1) * PAD + lane] = tanh_f(o1);
        loB[(i0 + 2) * PAD + lane] = tanh_f(o2);
        loB[(i0 + 3) * PAD + lane] = tanh_f(o3);
    }
    __syncthreads();

    // ---- Phase C: xg2[s][g] = bias + to[s]·l2_wih[g], SGPR weights -> tvB ----
    if (w < 2) {
        const int srow = w * 64 + lane;
        if (srow < SS) {
            float toRow[HH];
            #pragma unroll
            for (int d = 0; d < HH; d++) toRow[d] = loB[srow * PAD + d];
            for (int gg = 0; gg < HH; gg++) {
                float a0 = 0.f, a1 = 0.f, a2 = 0.f, a3 = 0.f;
                #pragma unroll
                for (int d = 0; d < HH; d += 4) {
                    a0 += toRow[d]     * l2_wih[gg * HH + d];
                    a1 += toRow[d + 1] * l2_wih[gg * HH + d + 1];
                    a2 += toRow[d + 2] * l2_wih[gg * HH + d + 2];
                    a3 += toRow[d + 3] * l2_wih[gg * HH + d + 3];
                }
                tvB[srow * PAD + gg] = l2_bih[gg] + l2_bhh[gg] + (a0 + a1) + (a2 + a3);
            }
        }
    }
    __syncthreads();

    // ---- Phase D: LSTM2 scan, wave 0, shuffles (h,c replicated per 16) ----
    if (t < 64) {
        float whr[H2];
        #pragma unroll
        for (int j = 0; j < H2; j++) whr[j] = l2_whh[lane * H2 + j];
        const int myi = lane & 15;
        float h = 0.0f, c = 0.0f;
        for (int s = 0; s < SS; s++) {
            float a = tvB[s * PAD + lane];
            #pragma unroll
            for (int j = 0; j < H2; j++) a += rl(h, j) * whr[j];
            float iv = __shfl(a, myi);
            float fv = __shfl(a, H2 + myi);
            float gv = __shfl(a, 2 * H2 + myi);
            float ov = __shfl(a, 3 * H2 + myi);
            c = sigm(fv) * c + sigm(iv) * tanh_f(gv);
            h = sigm(ov) * tanh_f(c);
            if (lane < H2) hsb[s * 17 + lane] = h;
        }
    }
    __syncthreads();

    // ---- Phase E: fc, lane = row, SGPR weights ----
    if (w < 2) {
        const int srow = w * 64 + lane;
        if (srow < SS) {
            float hreg[H2];
            #pragma unroll
            for (int j = 0; j < H2; j++) hreg[j] = hsb[srow * 17 + j];
            float* op = out + (size_t)b * SS * DD + srow * DD;
            for (int d = 0; d < DD; d++) {
                float a = fc_b[d];
                #pragma unroll
                for (int j = 0; j < H2; j++) a += hreg[j] * fc_w[d * H2 + j];
                op[d] = a;
            }
        }
    }
}

extern "C" void kernel_launch(void* const* d_in, const int* in_sizes, int n_in,
                              void* d_out, int out_size, void* d_ws, size_t ws_size,
                              hipStream_t stream) {
    const float* x     = (const float*)d_in[0];
    const float* fv_w  = (const float*)d_in[1];
    const float* fv_b  = (const float*)d_in[2];
    const float* fk_w  = (const float*)d_in[3];
    const float* fk_b  = (const float*)d_in[4];
    const float* fq_w  = (const float*)d_in[5];
    const float* fq_b  = (const float*)d_in[6];
    const float* l1f_wih = (const float*)d_in[7];
    const float* l1f_whh = (const float*)d_in[8];
    const float* l1f_bih = (const float*)d_in[9];
    const float* l1f_bhh = (const float*)d_in[10];
    const float* l1b_wih = (const float*)d_in[11];
    const float* l1b_whh = (const float*)d_in[12];
    const float* l1b_bih = (const float*)d_in[13];
    const float* l1b_bhh = (const float*)d_in[14];
    const float* tv_w  = (const float*)d_in[15];
    const float* tv_b  = (const float*)d_in[16];
    const float* tk_w  = (const float*)d_in[17];
    const float* tk_b  = (const float*)d_in[18];
    const float* tq_w  = (const float*)d_in[19];
    const float* tq_b  = (const float*)d_in[20];
    const float* l2_wih = (const float*)d_in[21];
    const float* l2_whh = (const float*)d_in[22];
    const float* l2_bih = (const float*)d_in[23];
    const float* l2_bhh = (const float*)d_in[24];
    const float* fc_w  = (const float*)d_in[25];
    const float* fc_b  = (const float*)d_in[26];

    float* fa = (float*)d_ws;                       // B*S*D floats
    float* lo = fa + (size_t)BB * SS * DD;          // B*S*H floats

    k_feat<<<BB, 256, 0, stream>>>(x, fv_w, fv_b, fk_w, fk_b, fq_w, fq_b, fa);
    k_bilstm<<<BB, 512, 0, stream>>>(fa,
        l1f_wih, l1f_whh, l1f_bih, l1f_bhh,
        l1b_wih, l1b_whh, l1b_bih, l1b_bhh, lo);
    k_temporal<<<BB, 512, 0, stream>>>(lo,
        tv_w, tv_b, tk_w, tk_b, tq_w, tq_b,
        l2_wih, l2_whh, l2_bih, l2_bhh, fc_w, fc_b,
        (float*)d_out);
}